// Round 11
// baseline (196.048 us; speedup 1.0000x reference)
//
#include <hip/hip_runtime.h>
#include <hip/hip_bf16.h>

#define NT 4096   // tokens
#define CD 768    // channels
#define NH 12     // heads
#define HD 64     // head dim
#define CQ 2304   // 3*CD

typedef __bf16 bf;
typedef __bf16 v8bf __attribute__((ext_vector_type(8)));
typedef __bf16 v4bf __attribute__((ext_vector_type(4)));
typedef float  v4f  __attribute__((ext_vector_type(4)));

// async global->LDS, 16B per lane; LDS dest is wave-uniform base + lane*16
__device__ __forceinline__ void gld16(const bf* g, bf* l) {
  __builtin_amdgcn_global_load_lds(
      (__attribute__((address_space(1))) void*)g,
      (__attribute__((address_space(3))) void*)l,
      16, 0, 0);
}

__device__ __forceinline__ float fexp2(float x) {
#if defined(__HIP_DEVICE_COMPILE__)
  return __builtin_amdgcn_exp2f(x);
#else
  return x;  // host pass never executes device code
#endif
}

// ---------- merged prep: fp32->bf16 cast of x  +  transpose-cast of both weights ----------
__global__ __launch_bounds__(256) void prep(
    const float* __restrict__ x, const float* __restrict__ wqkv,
    const float* __restrict__ wproj, bf* __restrict__ Xb,
    bf* __restrict__ WqkvT, bf* __restrict__ WpT) {
  __shared__ float tile[32][33];
  const int b = blockIdx.x, tid = threadIdx.x;
  if (b < 3072) {
    const int i = b * 256 + tid;  // n4 = 786432 = 3072*256 exactly
    const float4 v = ((const float4*)x)[i];
    bf o4[4] = {(bf)v.x, (bf)v.y, (bf)v.z, (bf)v.w};
    ((ushort4*)Xb)[i] = *(const ushort4*)o4;
    return;
  }
  const float* in;
  bf* out;
  int rows, cols, c0, r0;
  if (b < 4800) {
    const int t = b - 3072;           // 72 col-blocks x 24 row-blocks
    in = wqkv; out = WqkvT; rows = CD; cols = CQ;
    c0 = (t % 72) * 32; r0 = (t / 72) * 32;
  } else {
    const int t = b - 4800;           // 24 x 24
    in = wproj; out = WpT; rows = CD; cols = CD;
    c0 = (t % 24) * 32; r0 = (t / 24) * 32;
  }
  const int tx = tid & 31, ty = tid >> 5;  // 32 x 8
#pragma unroll
  for (int j = 0; j < 32; j += 8)
    tile[ty + j][tx] = in[(size_t)(r0 + ty + j) * cols + (c0 + tx)];
  __syncthreads();
#pragma unroll
  for (int j = 0; j < 32; j += 8)
    out[(size_t)(c0 + ty + j) * rows + (r0 + tx)] = (bf)tile[tx][ty + j];
}

// ------------- QKV GEMM: Xb[4096x768] * WqkvT[2304x768]^T, double-buffered K-loop ------------
// V is written TRANSPOSED with the per-32-key PV slot permutation baked in.
__global__ __launch_bounds__(256, 3) void gemm_qkv(
    const bf* __restrict__ A, const bf* __restrict__ Bt,
    bf* __restrict__ Qb, bf* __restrict__ Kb, bf* __restrict__ Vtb) {
  __shared__ __align__(16) bf As[2][128 * 32];
  __shared__ __align__(16) bf Bs[2][128 * 32];
  const int tid = threadIdx.x;
  const int lane = tid & 63, wave = tid >> 6;
  const int lane15 = lane & 15, quad = lane >> 4;
  const int waveM = wave & 1, waveN = wave >> 1;
  const int bm = blockIdx.x * 128;
  const int bn = blockIdx.y * 128;

  v4f acc[4][4];
#pragma unroll
  for (int i = 0; i < 4; ++i)
#pragma unroll
    for (int j = 0; j < 4; ++j) acc[i][j] = (v4f){0.f, 0.f, 0.f, 0.f};

  auto stageG = [&](int half, int k0) {
#pragma unroll
    for (int p = 0; p < 2; ++p) {
      const int t = tid + p * 256;
      const int r = t >> 2, c = (t & 3) * 8;
      gld16(A + (size_t)(bm + r) * CD + k0 + c, As[half] + t * 8);
    }
#pragma unroll
    for (int p = 0; p < 2; ++p) {
      const int t = tid + p * 256;
      const int r = t >> 2, c = (t & 3) * 8;
      gld16(Bt + (size_t)(bn + r) * CD + k0 + c, Bs[half] + t * 8);
    }
  };

  stageG(0, 0);
  asm volatile("s_waitcnt vmcnt(0)" ::: "memory");
  __syncthreads();

  for (int it = 0; it < CD / 32; ++it) {
    const int half = it & 1;
    if (it + 1 < CD / 32) stageG(half ^ 1, (it + 1) * 32);  // async, lands during compute

    v8bf af[4], bfr[4];
#pragma unroll
    for (int mt = 0; mt < 4; ++mt)
      af[mt] = *(const v8bf*)(As[half] + (waveM * 64 + mt * 16 + lane15) * 32 + quad * 8);
#pragma unroll
    for (int nt = 0; nt < 4; ++nt)
      bfr[nt] = *(const v8bf*)(Bs[half] + (waveN * 64 + nt * 16 + lane15) * 32 + quad * 8);
#pragma unroll
    for (int mt = 0; mt < 4; ++mt)
#pragma unroll
      for (int nt = 0; nt < 4; ++nt)
        acc[mt][nt] = __builtin_amdgcn_mfma_f32_16x16x32_bf16(af[mt], bfr[nt], acc[mt][nt], 0, 0, 0);

    asm volatile("s_waitcnt vmcnt(0)" ::: "memory");  // next tile landed (issued pre-compute)
    __syncthreads();
  }

  const float QSCALE = 0.125f * 1.4426950408889634f;  // fold D^-0.5 * log2(e)
#pragma unroll
  for (int mt = 0; mt < 4; ++mt) {
    const int rowB = bm + waveM * 64 + mt * 16 + quad * 4;
#pragma unroll
    for (int nt = 0; nt < 4; ++nt) {
      const int col = bn + waveN * 64 + nt * 16 + lane15;
      const int s = col / CD;
      const int rem = col - s * CD;
      const int h = rem >> 6, d = rem & 63;
      if (s == 2) {
        // 4 consecutive keys -> one 8B store at the PV-permuted position
        bf vp[4];
#pragma unroll
        for (int i = 0; i < 4; ++i) vp[i] = (bf)acc[mt][nt][i];
        const int pos = (rowB & ~31) + (((rowB & 15) >> 2) << 3) + (((rowB >> 4) & 1) << 2);
        *(uint2*)(Vtb + ((size_t)h * HD + d) * NT + pos) = *(const uint2*)vp;
      } else {
#pragma unroll
        for (int i = 0; i < 4; ++i) {
          const float v = acc[mt][nt][i];
          const int row = rowB + i;
          if (s == 0) Qb[((size_t)h * NT + row) * HD + d] = (bf)(v * QSCALE);
          else        Kb[((size_t)h * NT + row) * HD + d] = (bf)v;
        }
      }
    }
  }
}

// ------------- attention: block = 1 head x 64 Q rows; wave = 32-key quarter x all 64 Q rows --
// 48 KB LDS (K double-buffered, V single-buffered with graded vmcnt) -> 3 blocks/CU,
// 768 blocks = exactly one round. Never drains vmcnt to 0 mid-loop.
__global__ __launch_bounds__(256, 3) void attn(
    const bf* __restrict__ Qb, const bf* __restrict__ Kb,
    const bf* __restrict__ Vtb, bf* __restrict__ Ob) {
  __shared__ __align__(16) char smem[49152];  // [K0 16K][K1 16K][V 16K]
  float* Red = (float*)smem;                  // epilogue reuse (33 KB needed)

  // head->XCD affinity: blocks of one head land on one XCD (b%8 round-robin heuristic)
  const int b = blockIdx.x;
  int h, qt;
  if (b < 512) { h = b & 7;        qt = b >> 3; }
  else { const int bb = b - 512; h = 8 + (bb & 3); qt = bb >> 2; }
  const int q0 = qt * 64;

  const int tid = threadIdx.x;
  const int wave = tid >> 6, lane = tid & 63;
  const int lane15 = lane & 15, quad = lane >> 4;

  const bf* Kh = Kb + (size_t)h * NT * HD;
  const bf* Vh = Vtb + (size_t)h * HD * NT;

  // Q fragments for all 4 sub-tiles (B-operand: n=lane15=Q row, k=quad*8+j=dim)
  v8bf aQ[4][2];
#pragma unroll
  for (int sub = 0; sub < 4; ++sub) {
    const int qrow = q0 + sub * 16 + lane15;
    aQ[sub][0] = *(const v8bf*)(Qb + ((size_t)h * NT + qrow) * HD + quad * 8);
    aQ[sub][1] = *(const v8bf*)(Qb + ((size_t)h * NT + qrow) * HD + 32 + quad * 8);
  }

  v4f o[4][4];
#pragma unroll
  for (int sub = 0; sub < 4; ++sub)
#pragma unroll
    for (int dt = 0; dt < 4; ++dt) o[sub][dt] = (v4f){0.f, 0.f, 0.f, 0.f};
  float lsum[4] = {0.f, 0.f, 0.f, 0.f};

  // 4 gld16 each; source-side XOR swizzle (dest order fixed by gld16)
  auto stageK = [&](int half, int kt) {
    bf* Kdst = (bf*)(smem + half * 16384);
#pragma unroll
    for (int p = 0; p < 4; ++p) {
      const int L = p * 256 + tid;
      const int r = L >> 3, u = L & 7;
      gld16(Kh + (size_t)(kt + r) * HD + ((u ^ (r & 7)) << 3), Kdst + L * 8);
    }
  };
  auto stageV = [&](int kt) {
    bf* Vdst = (bf*)(smem + 32768);
#pragma unroll
    for (int p = 0; p < 4; ++p) {
      const int L = p * 256 + tid;
      const int d = L >> 4, u = L & 15;
      gld16(Vh + (size_t)d * NT + kt + ((u ^ (d & 15)) << 3), Vdst + L * 8);
    }
  };

  stageK(0, 0);
  stageV(0);
  stageK(1, 128);
  asm volatile("s_waitcnt vmcnt(4)" ::: "memory");  // K0,V0 done; K1 in flight
  __syncthreads();

  const int NIT = NT / 128;  // 32
  for (int it = 0; it < NIT; ++it) {
    const int half = it & 1;
    // ensure K(it) landed (issued >=1.5 iters ago); keep V(it+?)/K in flight
    if (it > 0) {
      if (it < NIT - 1) asm volatile("s_waitcnt vmcnt(8)" ::: "memory");
      else              asm volatile("s_waitcnt vmcnt(4)" ::: "memory");
    }
    const bf* Kbuf = (const bf*)(smem + half * 16384);
    const bf* Vbuf = (const bf*)(smem + 32768);

    // S^T = K Q^T on this wave's 32 keys (2 chunks of 16) x all 64 Q rows
    v4bf aPlo[4], aPhi[4];
#pragma unroll
    for (int e = 0; e < 2; ++e) {
      const int k = (wave * 2 + e) * 16 + lane15;
      const int k7 = k & 7;
      const v8bf bk0 = *(const v8bf*)(Kbuf + k * 64 + ((quad ^ k7) << 3));
      const v8bf bk1 = *(const v8bf*)(Kbuf + k * 64 + (((quad ^ 4) ^ k7) << 3));
#pragma unroll
      for (int sub = 0; sub < 4; ++sub) {
        v4f z = (v4f){0.f, 0.f, 0.f, 0.f};
        z = __builtin_amdgcn_mfma_f32_16x16x32_bf16(bk0, aQ[sub][0], z, 0, 0, 0);
        z = __builtin_amdgcn_mfma_f32_16x16x32_bf16(bk1, aQ[sub][1], z, 0, 0, 0);
        v4bf p4;
#pragma unroll
        for (int r = 0; r < 4; ++r) {
          const float p = fexp2(z[r]);
          lsum[sub] += p;
          p4[r] = (bf)p;
        }
        if (e == 0) aPlo[sub] = p4; else aPhi[sub] = p4;
      }
    }

    // ensure V(it) landed (issued last iter; covered by QK+exp above)
    if (it < NIT - 1) asm volatile("s_waitcnt vmcnt(4)" ::: "memory");
    else              asm volatile("s_waitcnt vmcnt(0)" ::: "memory");

    // O += P V on this wave's 32 keys (x32 MFMA; A slot order == V position order)
#pragma unroll
    for (int dt = 0; dt < 4; ++dt) {
      const int d = dt * 16 + lane15;
      const v8bf bv = *(const v8bf*)(Vbuf + d * 128 + (((wave * 4 + quad) ^ lane15) << 3));
#pragma unroll
      for (int sub = 0; sub < 4; ++sub) {
        const v8bf aP8 = __builtin_shufflevector(aPlo[sub], aPhi[sub], 0, 1, 2, 3, 4, 5, 6, 7);
        o[sub][dt] = __builtin_amdgcn_mfma_f32_16x16x32_bf16(aP8, bv, o[sub][dt], 0, 0, 0);
      }
    }

    __syncthreads();  // all waves done reading K[half] and V(it)
    if (it + 1 < NIT) stageV((it + 1) * 128);          // V(it+1) into the single V buffer
    if (it + 2 < NIT) stageK(half, (it + 2) * 128);    // K(it+2) into the buffer just freed
  }

  // quad-reduce denoms: lane then holds denom partial (this wave's 32 keys) for Qrow=lane15
#pragma unroll
  for (int sub = 0; sub < 4; ++sub) {
    lsum[sub] += __shfl_xor(lsum[sub], 16, 64);
    lsum[sub] += __shfl_xor(lsum[sub], 32, 64);
  }

  // cross-wave combine, two phases of 2 subs. Region rw=wave*2+sl: 1024 f; lsum @ 8192.
#pragma unroll
  for (int sp = 0; sp < 2; ++sp) {
    __syncthreads();
#pragma unroll
    for (int sl = 0; sl < 2; ++sl) {
      const int s = sp * 2 + sl;
      float* reg = Red + (wave * 2 + sl) * 1024;
#pragma unroll
      for (int dt = 0; dt < 4; ++dt)
        *(v4f*)(reg + dt * 256 + lane15 * 16 + quad * 4) = o[s][dt];
      if (quad == 0) Red[8192 + (wave * 2 + sl) * 16 + lane15] = lsum[s];
    }
    __syncthreads();
    const int wlo = sp * 2;
    if (wave == wlo || wave == wlo + 1) {
      const int sl = wave - wlo;
      const int s = sp * 2 + sl;
      float den = 0.f;
#pragma unroll
      for (int wv = 0; wv < 4; ++wv) den += Red[8192 + (wv * 2 + sl) * 16 + lane15];
      const float linv = 1.f / den;
#pragma unroll
      for (int dt = 0; dt < 4; ++dt) {
        v4f sum = (v4f){0.f, 0.f, 0.f, 0.f};
#pragma unroll
        for (int wv = 0; wv < 4; ++wv)
          sum += *(const v4f*)(Red + (wv * 2 + sl) * 1024 + dt * 256 + lane15 * 16 + quad * 4);
#pragma unroll
        for (int i = 0; i < 4; ++i) {
          const float linv_i = __shfl(linv, quad * 4 + i, 64);
          const int row = q0 + s * 16 + quad * 4 + i;
          Ob[(size_t)row * CD + h * HD + dt * 16 + lane15] = (bf)(sum[i] * linv_i);
        }
      }
    }
  }
}

// ------------- proj GEMM: Ob[4096x768] * WpT[768x768]^T + bias, 64x128 tiles ----------------
// 384 blocks (was 192 -> 64 CUs idle); all-resident, double-buffered.
__global__ __launch_bounds__(256, 4) void gemm_proj(
    const bf* __restrict__ A, const bf* __restrict__ Bt,
    const float* __restrict__ bias, float* __restrict__ out) {
  __shared__ __align__(16) bf As[2][64 * 32];
  __shared__ __align__(16) bf Bs[2][128 * 32];
  const int tid = threadIdx.x;
  const int lane = tid & 63, wave = tid >> 6;
  const int lane15 = lane & 15, quad = lane >> 4;
  const int bm = blockIdx.x * 64;
  const int bn = blockIdx.y * 128;

  v4f acc[4][2];
#pragma unroll
  for (int i = 0; i < 4; ++i)
#pragma unroll
    for (int j = 0; j < 2; ++j) acc[i][j] = (v4f){0.f, 0.f, 0.f, 0.f};

  auto stageG = [&](int half, int k0) {
    {
      const int r = tid >> 2, c = (tid & 3) * 8;
      gld16(A + (size_t)(bm + r) * CD + k0 + c, As[half] + tid * 8);
    }
#pragma unroll
    for (int p = 0; p < 2; ++p) {
      const int t = tid + p * 256;
      const int r = t >> 2, c = (t & 3) * 8;
      gld16(Bt + (size_t)(bn + r) * CD + k0 + c, Bs[half] + t * 8);
    }
  };

  stageG(0, 0);
  asm volatile("s_waitcnt vmcnt(0)" ::: "memory");
  __syncthreads();

  for (int it = 0; it < CD / 32; ++it) {
    const int half = it & 1;
    if (it + 1 < CD / 32) stageG(half ^ 1, (it + 1) * 32);

    v8bf af[4], bfr[2];
#pragma unroll
    for (int mt = 0; mt < 4; ++mt)
      af[mt] = *(const v8bf*)(As[half] + (mt * 16 + lane15) * 32 + quad * 8);
#pragma unroll
    for (int nt = 0; nt < 2; ++nt)
      bfr[nt] = *(const v8bf*)(Bs[half] + (wave * 32 + nt * 16 + lane15) * 32 + quad * 8);
#pragma unroll
    for (int mt = 0; mt < 4; ++mt)
#pragma unroll
      for (int nt = 0; nt < 2; ++nt)
        acc[mt][nt] = __builtin_amdgcn_mfma_f32_16x16x32_bf16(af[mt], bfr[nt], acc[mt][nt], 0, 0, 0);

    asm volatile("s_waitcnt vmcnt(0)" ::: "memory");
    __syncthreads();
  }

#pragma unroll
  for (int mt = 0; mt < 4; ++mt) {
    const int rowB = bm + mt * 16 + quad * 4;
#pragma unroll
    for (int nt = 0; nt < 2; ++nt) {
      const int col = bn + wave * 32 + nt * 16 + lane15;
      const float bcol = bias[col];
#pragma unroll
      for (int i = 0; i < 4; ++i)
        out[(size_t)(rowB + i) * CD + col] = acc[mt][nt][i] + bcol;
    }
  }
}

extern "C" void kernel_launch(void* const* d_in, const int* in_sizes, int n_in,
                              void* d_out, int out_size, void* d_ws, size_t ws_size,
                              hipStream_t stream) {
  const float* x     = (const float*)d_in[0];   // [4096][768] fp32
  const float* wqkv  = (const float*)d_in[1];   // [768][2304] fp32
  const float* wproj = (const float*)d_in[2];   // [768][768]  fp32
  const float* bproj = (const float*)d_in[3];   // [768]       fp32
  float* out = (float*)d_out;                   // [4096][768] fp32

  bf* ws    = (bf*)d_ws;
  bf* Xb    = ws;  ws += (size_t)NT * CD;        // [4096][768] bf16
  bf* WqkvT = ws;  ws += (size_t)CQ * CD;        // [2304][768]
  bf* WpT   = ws;  ws += (size_t)CD * CD;        // [768][768]
  bf* Qb    = ws;  ws += (size_t)NH * NT * HD;   // [h][n][d], pre-scaled by 0.125*log2e
  bf* Kb    = ws;  ws += (size_t)NH * NT * HD;   // [h][n][d]
  bf* Vtb   = ws;  ws += (size_t)NH * NT * HD;   // [h][d][n], keys PV-slot-permuted per 32
  bf* Ob    = ws;  ws += (size_t)NT * CD;        // [n][h*64+d]

  prep<<<5376, 256, 0, stream>>>(x, wqkv, wproj, Xb, WqkvT, WpT);
  gemm_qkv<<<dim3(NT / 128, CQ / 128), 256, 0, stream>>>(Xb, WqkvT, Qb, Kb, Vtb);
  attn<<<768, 256, 0, stream>>>(Qb, Kb, Vtb, Ob);
  gemm_proj<<<dim3(NT / 64, CD / 128), 256, 0, stream>>>(Ob, WpT, bproj, out);
}

// Round 13
// 172.166 us; speedup vs baseline: 1.1387x; 1.1387x over previous
//
#include <hip/hip_runtime.h>
#include <hip/hip_bf16.h>

#define NT 4096   // tokens
#define CD 768    // channels
#define NH 12     // heads
#define HD 64     // head dim
#define CQ 2304   // 3*CD

typedef __bf16 bf;
typedef __bf16 v8bf __attribute__((ext_vector_type(8)));
typedef __bf16 v4bf __attribute__((ext_vector_type(4)));
typedef float  v4f  __attribute__((ext_vector_type(4)));

// async global->LDS, 16B per lane; LDS dest is wave-uniform base + lane*16
__device__ __forceinline__ void gld16(const bf* g, bf* l) {
  __builtin_amdgcn_global_load_lds(
      (__attribute__((address_space(1))) void*)g,
      (__attribute__((address_space(3))) void*)l,
      16, 0, 0);
}

__device__ __forceinline__ float fexp2(float x) {
#if defined(__HIP_DEVICE_COMPILE__)
  return __builtin_amdgcn_exp2f(x);
#else
  return x;  // host pass never executes device code
#endif
}

// ---------- merged prep: fp32->bf16 cast of x  +  transpose-cast of both weights ----------
__global__ __launch_bounds__(256) void prep(
    const float* __restrict__ x, const float* __restrict__ wqkv,
    const float* __restrict__ wproj, bf* __restrict__ Xb,
    bf* __restrict__ WqkvT, bf* __restrict__ WpT) {
  __shared__ float tile[32][33];
  const int b = blockIdx.x, tid = threadIdx.x;
  if (b < 3072) {
    const int i = b * 256 + tid;  // n4 = 786432 = 3072*256 exactly
    const float4 v = ((const float4*)x)[i];
    bf o4[4] = {(bf)v.x, (bf)v.y, (bf)v.z, (bf)v.w};
    ((ushort4*)Xb)[i] = *(const ushort4*)o4;
    return;
  }
  const float* in;
  bf* out;
  int rows, cols, c0, r0;
  if (b < 4800) {
    const int t = b - 3072;           // 72 col-blocks x 24 row-blocks
    in = wqkv; out = WqkvT; rows = CD; cols = CQ;
    c0 = (t % 72) * 32; r0 = (t / 72) * 32;
  } else {
    const int t = b - 4800;           // 24 x 24
    in = wproj; out = WpT; rows = CD; cols = CD;
    c0 = (t % 24) * 32; r0 = (t / 24) * 32;
  }
  const int tx = tid & 31, ty = tid >> 5;  // 32 x 8
#pragma unroll
  for (int j = 0; j < 32; j += 8)
    tile[ty + j][tx] = in[(size_t)(r0 + ty + j) * cols + (c0 + tx)];
  __syncthreads();
#pragma unroll
  for (int j = 0; j < 32; j += 8)
    out[(size_t)(c0 + ty + j) * rows + (r0 + tx)] = (bf)tile[tx][ty + j];
}

// ------------- QKV GEMM: Xb[4096x768] * WqkvT[2304x768]^T -------------
// BK=64 single-buffered (m97 pattern: stage -> vmcnt0 -> barrier -> compute -> barrier),
// 12 K-iterations, 32 MFMA per wave per iter. XOR swizzle (u^(r&7)) on staging source
// and fragment reads kills the 128B-stride bank conflicts.
// V is written TRANSPOSED with the per-32-key PV slot permutation baked in.
__global__ __launch_bounds__(256, 3) void gemm_qkv(
    const bf* __restrict__ A, const bf* __restrict__ Bt,
    bf* __restrict__ Qb, bf* __restrict__ Kb, bf* __restrict__ Vtb) {
  __shared__ __align__(16) bf As[128 * 64];   // 16 KB
  __shared__ __align__(16) bf Bs[128 * 64];   // 16 KB
  const int tid = threadIdx.x;
  const int lane = tid & 63, wave = tid >> 6;
  const int lane15 = lane & 15, quad = lane >> 4;
  const int waveM = wave & 1, waveN = wave >> 1;
  const int bm = blockIdx.x * 128;
  const int bn = blockIdx.y * 128;

  v4f acc[4][4];
#pragma unroll
  for (int i = 0; i < 4; ++i)
#pragma unroll
    for (int j = 0; j < 4; ++j) acc[i][j] = (v4f){0.f, 0.f, 0.f, 0.f};

  for (int k0 = 0; k0 < CD; k0 += 64) {
    // stage 128x64 A and B tiles, source-side XOR swizzle: unit u of row r holds
    // global dims ((u^(r&7))*8 ..+8)
#pragma unroll
    for (int p = 0; p < 4; ++p) {
      const int t = tid + p * 256;
      const int r = t >> 3, u = t & 7;
      gld16(A + (size_t)(bm + r) * CD + k0 + ((u ^ (r & 7)) << 3), As + t * 8);
    }
#pragma unroll
    for (int p = 0; p < 4; ++p) {
      const int t = tid + p * 256;
      const int r = t >> 3, u = t & 7;
      gld16(Bt + (size_t)(bn + r) * CD + k0 + ((u ^ (r & 7)) << 3), Bs + t * 8);
    }
    asm volatile("s_waitcnt vmcnt(0)" ::: "memory");
    __syncthreads();

    v8bf af[4][2], bfr[4][2];
#pragma unroll
    for (int mt = 0; mt < 4; ++mt) {
      const int rr = waveM * 64 + mt * 16 + lane15;
      const int r7 = rr & 7;
      af[mt][0] = *(const v8bf*)(As + rr * 64 + ((quad ^ r7) << 3));
      af[mt][1] = *(const v8bf*)(As + rr * 64 + (((quad ^ 4) ^ r7) << 3));
    }
#pragma unroll
    for (int nt = 0; nt < 4; ++nt) {
      const int rr = waveN * 64 + nt * 16 + lane15;
      const int r7 = rr & 7;
      bfr[nt][0] = *(const v8bf*)(Bs + rr * 64 + ((quad ^ r7) << 3));
      bfr[nt][1] = *(const v8bf*)(Bs + rr * 64 + (((quad ^ 4) ^ r7) << 3));
    }
#pragma unroll
    for (int mt = 0; mt < 4; ++mt)
#pragma unroll
      for (int nt = 0; nt < 4; ++nt) {
        acc[mt][nt] = __builtin_amdgcn_mfma_f32_16x16x32_bf16(af[mt][0], bfr[nt][0], acc[mt][nt], 0, 0, 0);
        acc[mt][nt] = __builtin_amdgcn_mfma_f32_16x16x32_bf16(af[mt][1], bfr[nt][1], acc[mt][nt], 0, 0, 0);
      }
    __syncthreads();
  }

  const float QSCALE = 0.125f * 1.4426950408889634f;  // fold D^-0.5 * log2(e)
#pragma unroll
  for (int mt = 0; mt < 4; ++mt) {
    const int rowB = bm + waveM * 64 + mt * 16 + quad * 4;
#pragma unroll
    for (int nt = 0; nt < 4; ++nt) {
      const int col = bn + waveN * 64 + nt * 16 + lane15;
      const int s = col / CD;
      const int rem = col - s * CD;
      const int h = rem >> 6, d = rem & 63;
      if (s == 2) {
        // 4 consecutive keys -> one 8B store at the PV-permuted position
        bf vp[4];
#pragma unroll
        for (int i = 0; i < 4; ++i) vp[i] = (bf)acc[mt][nt][i];
        const int pos = (rowB & ~31) + (((rowB & 15) >> 2) << 3) + (((rowB >> 4) & 1) << 2);
        *(uint2*)(Vtb + ((size_t)h * HD + d) * NT + pos) = *(const uint2*)vp;
      } else {
#pragma unroll
        for (int i = 0; i < 4; ++i) {
          const float v = acc[mt][nt][i];
          const int row = rowB + i;
          if (s == 0) Qb[((size_t)h * NT + row) * HD + d] = (bf)(v * QSCALE);
          else        Kb[((size_t)h * NT + row) * HD + d] = (bf)v;
        }
      }
    }
  }
}

// ------------- attention (R10-verified): block = 1 head x 64 Q rows; wave = 32-key quarter ---
// max-free softmax; P in registers; K/V double-buffered in LDS via global_load_lds with
// XOR swizzle applied on the GLOBAL source side (gld16 dest order is fixed).
// Keep the vmcnt(0)+barrier pattern: vmcnt alone does NOT order the DMA LDS write
// against an immediately-following ds_read (R12 failure).
__global__ __launch_bounds__(256, 2) void attn(
    const bf* __restrict__ Qb, const bf* __restrict__ Kb,
    const bf* __restrict__ Vtb, bf* __restrict__ Ob) {
  __shared__ __align__(16) char smem[65536];  // [K0 16K][V0 16K][K1 16K][V1 16K]
  float* Red = (float*)smem;                  // epilogue reuse

  // head->XCD affinity: blocks of one head land on one XCD (b%8 round-robin heuristic)
  const int b = blockIdx.x;
  int h, qt;
  if (b < 512) { h = b & 7;        qt = b >> 3; }
  else { const int bb = b - 512; h = 8 + (bb & 3); qt = bb >> 2; }
  const int q0 = qt * 64;

  const int tid = threadIdx.x;
  const int wave = tid >> 6, lane = tid & 63;
  const int lane15 = lane & 15, quad = lane >> 4;

  const bf* Kh = Kb + (size_t)h * NT * HD;
  const bf* Vh = Vtb + (size_t)h * HD * NT;

  // Q fragments for all 4 sub-tiles (B-operand: n=lane15=Q row, k=quad*8+j=dim)
  v8bf aQ[4][2];
#pragma unroll
  for (int sub = 0; sub < 4; ++sub) {
    const int qrow = q0 + sub * 16 + lane15;
    aQ[sub][0] = *(const v8bf*)(Qb + ((size_t)h * NT + qrow) * HD + quad * 8);
    aQ[sub][1] = *(const v8bf*)(Qb + ((size_t)h * NT + qrow) * HD + 32 + quad * 8);
  }

  v4f o[4][4];
#pragma unroll
  for (int sub = 0; sub < 4; ++sub)
#pragma unroll
    for (int dt = 0; dt < 4; ++dt) o[sub][dt] = (v4f){0.f, 0.f, 0.f, 0.f};
  float lsum[4] = {0.f, 0.f, 0.f, 0.f};

  // stage tile kt into buffer half `half` (0 or 1): 8 gld16, no VGPR round-trip.
  auto stage = [&](int half, int kt) {
    bf* Kdst = (bf*)(smem + half * 32768);
    bf* Vdst = (bf*)(smem + half * 32768 + 16384);
#pragma unroll
    for (int p = 0; p < 4; ++p) {
      const int L = p * 256 + tid;
      const int r = L >> 3, u = L & 7;
      gld16(Kh + (size_t)(kt + r) * HD + ((u ^ (r & 7)) << 3), Kdst + L * 8);
    }
#pragma unroll
    for (int p = 0; p < 4; ++p) {
      const int L = p * 256 + tid;
      const int d = L >> 4, u = L & 15;
      gld16(Vh + (size_t)d * NT + kt + ((u ^ (d & 15)) << 3), Vdst + L * 8);
    }
  };

  stage(0, 0);
  asm volatile("s_waitcnt vmcnt(0)" ::: "memory");
  __syncthreads();

  for (int it = 0; it < NT / 128; ++it) {
    const int half = it & 1;
    if (it + 1 < NT / 128) stage(half ^ 1, (it + 1) * 128);  // async, lands during compute

    const bf* Kbuf = (const bf*)(smem + half * 32768);
    const bf* Vbuf = (const bf*)(smem + half * 32768 + 16384);

    // S^T = K Q^T on this wave's 32 keys (2 chunks of 16) x all 64 Q rows
    v4bf aPlo[4], aPhi[4];
#pragma unroll
    for (int e = 0; e < 2; ++e) {
      const int k = (wave * 2 + e) * 16 + lane15;
      const int k7 = k & 7;
      const v8bf bk0 = *(const v8bf*)(Kbuf + k * 64 + ((quad ^ k7) << 3));
      const v8bf bk1 = *(const v8bf*)(Kbuf + k * 64 + (((quad ^ 4) ^ k7) << 3));
#pragma unroll
      for (int sub = 0; sub < 4; ++sub) {
        v4f z = (v4f){0.f, 0.f, 0.f, 0.f};
        z = __builtin_amdgcn_mfma_f32_16x16x32_bf16(bk0, aQ[sub][0], z, 0, 0, 0);
        z = __builtin_amdgcn_mfma_f32_16x16x32_bf16(bk1, aQ[sub][1], z, 0, 0, 0);
        v4bf p4;
#pragma unroll
        for (int r = 0; r < 4; ++r) {
          const float p = fexp2(z[r]);
          lsum[sub] += p;
          p4[r] = (bf)p;
        }
        if (e == 0) aPlo[sub] = p4; else aPhi[sub] = p4;
      }
    }

    // O += P V on this wave's 32 keys (x32 MFMA; A slot order == V position order)
#pragma unroll
    for (int dt = 0; dt < 4; ++dt) {
      const int d = dt * 16 + lane15;
      const v8bf bv = *(const v8bf*)(Vbuf + d * 128 + (((wave * 4 + quad) ^ lane15) << 3));
#pragma unroll
      for (int sub = 0; sub < 4; ++sub) {
        const v8bf aP8 = __builtin_shufflevector(aPlo[sub], aPhi[sub], 0, 1, 2, 3, 4, 5, 6, 7);
        o[sub][dt] = __builtin_amdgcn_mfma_f32_16x16x32_bf16(aP8, bv, o[sub][dt], 0, 0, 0);
      }
    }

    asm volatile("s_waitcnt vmcnt(0)" ::: "memory");  // next-tile loads landed
    __syncthreads();
  }

  // quad-reduce denoms: lane then holds denom partial (this wave's 32 keys) for Qrow=lane15
#pragma unroll
  for (int sub = 0; sub < 4; ++sub) {
    lsum[sub] += __shfl_xor(lsum[sub], 16, 64);
    lsum[sub] += __shfl_xor(lsum[sub], 32, 64);
  }

  // cross-wave combine, two phases of 2 subs. Region rw=wave*2+sl: 1024 f; lsum @ 8192.
#pragma unroll
  for (int sp = 0; sp < 2; ++sp) {
    __syncthreads();
#pragma unroll
    for (int sl = 0; sl < 2; ++sl) {
      const int s = sp * 2 + sl;
      float* reg = Red + (wave * 2 + sl) * 1024;
#pragma unroll
      for (int dt = 0; dt < 4; ++dt)
        *(v4f*)(reg + dt * 256 + lane15 * 16 + quad * 4) = o[s][dt];
      if (quad == 0) Red[8192 + (wave * 2 + sl) * 16 + lane15] = lsum[s];
    }
    __syncthreads();
    const int wlo = sp * 2;
    if (wave == wlo || wave == wlo + 1) {
      const int sl = wave - wlo;
      const int s = sp * 2 + sl;
      float den = 0.f;
#pragma unroll
      for (int wv = 0; wv < 4; ++wv) den += Red[8192 + (wv * 2 + sl) * 16 + lane15];
      const float linv = 1.f / den;
#pragma unroll
      for (int dt = 0; dt < 4; ++dt) {
        v4f sum = (v4f){0.f, 0.f, 0.f, 0.f};
#pragma unroll
        for (int wv = 0; wv < 4; ++wv)
          sum += *(const v4f*)(Red + (wv * 2 + sl) * 1024 + dt * 256 + lane15 * 16 + quad * 4);
#pragma unroll
        for (int i = 0; i < 4; ++i) {
          const float linv_i = __shfl(linv, quad * 4 + i, 64);
          const int row = q0 + s * 16 + quad * 4 + i;
          Ob[(size_t)row * CD + h * HD + dt * 16 + lane15] = (bf)(sum[i] * linv_i);
        }
      }
    }
  }
}

// ------------- proj GEMM: Ob[4096x768] * WpT[768x768]^T + bias, 64x128 tiles ----------------
__global__ __launch_bounds__(256, 4) void gemm_proj(
    const bf* __restrict__ A, const bf* __restrict__ Bt,
    const float* __restrict__ bias, float* __restrict__ out) {
  __shared__ __align__(16) bf As[2][64 * 32];
  __shared__ __align__(16) bf Bs[2][128 * 32];
  const int tid = threadIdx.x;
  const int lane = tid & 63, wave = tid >> 6;
  const int lane15 = lane & 15, quad = lane >> 4;
  const int bm = blockIdx.x * 64;
  const int bn = blockIdx.y * 128;

  v4f acc[4][2];
#pragma unroll
  for (int i = 0; i < 4; ++i)
#pragma unroll
    for (int j = 0; j < 2; ++j) acc[i][j] = (v4f){0.f, 0.f, 0.f, 0.f};

  auto stageG = [&](int half, int k0) {
    {
      const int r = tid >> 2, c = (tid & 3) * 8;
      gld16(A + (size_t)(bm + r) * CD + k0 + c, As[half] + tid * 8);
    }
#pragma unroll
    for (int p = 0; p < 2; ++p) {
      const int t = tid + p * 256;
      const int r = t >> 2, c = (t & 3) * 8;
      gld16(Bt + (size_t)(bn + r) * CD + k0 + c, Bs[half] + t * 8);
    }
  };

  stageG(0, 0);
  asm volatile("s_waitcnt vmcnt(0)" ::: "memory");
  __syncthreads();

  for (int it = 0; it < CD / 32; ++it) {
    const int half = it & 1;
    if (it + 1 < CD / 32) stageG(half ^ 1, (it + 1) * 32);

    v8bf af[4], bfr[2];
#pragma unroll
    for (int mt = 0; mt < 4; ++mt)
      af[mt] = *(const v8bf*)(As[half] + (mt * 16 + lane15) * 32 + quad * 8);
#pragma unroll
    for (int nt = 0; nt < 2; ++nt)
      bfr[nt] = *(const v8bf*)(Bs[half] + (wave * 32 + nt * 16 + lane15) * 32 + quad * 8);
#pragma unroll
    for (int mt = 0; mt < 4; ++mt)
#pragma unroll
      for (int nt = 0; nt < 2; ++nt)
        acc[mt][nt] = __builtin_amdgcn_mfma_f32_16x16x32_bf16(af[mt], bfr[nt], acc[mt][nt], 0, 0, 0);

    asm volatile("s_waitcnt vmcnt(0)" ::: "memory");
    __syncthreads();
  }

#pragma unroll
  for (int mt = 0; mt < 4; ++mt) {
    const int rowB = bm + mt * 16 + quad * 4;
#pragma unroll
    for (int nt = 0; nt < 2; ++nt) {
      const int col = bn + wave * 32 + nt * 16 + lane15;
      const float bcol = bias[col];
#pragma unroll
      for (int i = 0; i < 4; ++i)
        out[(size_t)(rowB + i) * CD + col] = acc[mt][nt][i] + bcol;
    }
  }
}

extern "C" void kernel_launch(void* const* d_in, const int* in_sizes, int n_in,
                              void* d_out, int out_size, void* d_ws, size_t ws_size,
                              hipStream_t stream) {
  const float* x     = (const float*)d_in[0];   // [4096][768] fp32
  const float* wqkv  = (const float*)d_in[1];   // [768][2304] fp32
  const float* wproj = (const float*)d_in[2];   // [768][768]  fp32
  const float* bproj = (const float*)d_in[3];   // [768]       fp32
  float* out = (float*)d_out;                   // [4096][768] fp32

  bf* ws    = (bf*)d_ws;
  bf* Xb    = ws;  ws += (size_t)NT * CD;        // [4096][768] bf16
  bf* WqkvT = ws;  ws += (size_t)CQ * CD;        // [2304][768]
  bf* WpT   = ws;  ws += (size_t)CD * CD;        // [768][768]
  bf* Qb    = ws;  ws += (size_t)NH * NT * HD;   // [h][n][d], pre-scaled by 0.125*log2e
  bf* Kb    = ws;  ws += (size_t)NH * NT * HD;   // [h][n][d]
  bf* Vtb   = ws;  ws += (size_t)NH * NT * HD;   // [h][d][n], keys PV-slot-permuted per 32
  bf* Ob    = ws;  ws += (size_t)NT * CD;        // [n][h*64+d]

  prep<<<5376, 256, 0, stream>>>(x, wqkv, wproj, Xb, WqkvT, WpT);
  gemm_qkv<<<dim3(NT / 128, CQ / 128), 256, 0, stream>>>(Xb, WqkvT, Qb, Kb, Vtb);
  attn<<<768, 256, 0, stream>>>(Qb, Kb, Vtb, Ob);
  gemm_proj<<<dim3(NT / 64, CD / 128), 256, 0, stream>>>(Ob, WpT, bproj, out);
}